// Round 11
// baseline (272.063 us; speedup 1.0000x reference)
//
#include <hip/hip_runtime.h>
#include <hip/hip_bf16.h>
#include <hip/hip_fp16.h>

// ---------------------------------------------------------------------------
// GCN link prediction (math fp32, fp16 tables, MFMA GEMMs):
//   prep | count4(shadowed atomics) -> deg/partials(+shadow prefix) ->
//   scan(2-level) -> CSR fill(no atomic) -> mfma gemm1 -> agg128 relu ->
//   mfma gemm2 -> agg64 -> decode
// Round 11 = round-10 passing code with: (a) prep/count unfused (fusion was
// a mistake), (b) counting atomics spread over 4 shadow arrays to cut
// cache-line contention 4x; fill uses per-node shadow prefixes.
// ---------------------------------------------------------------------------

typedef _Float16 half8 __attribute__((ext_vector_type(8)));
typedef _Float16 half4v __attribute__((ext_vector_type(4)));
typedef float   floatx4 __attribute__((ext_vector_type(4)));

// Convert x -> fp16 Xh; W1/W2 -> fp16 transposed (round-9 verbatim).
__global__ __launch_bounds__(256)
void prep_kernel(const float* __restrict__ x, const float* __restrict__ W1,
                 const float* __restrict__ W2, _Float16* __restrict__ Xh,
                 _Float16* __restrict__ W1t, _Float16* __restrict__ W2t, int n4) {
  int i = blockIdx.x * 256 + threadIdx.x;
  if (i < n4) {
    float4 v = ((const float4*)x)[i];
    half4v h; h[0] = (_Float16)v.x; h[1] = (_Float16)v.y;
    h[2] = (_Float16)v.z; h[3] = (_Float16)v.w;
    ((half4v*)Xh)[i] = h;
  }
  if (i < 128 * 128) {  // W1t[n*128+k] = W1[k*128+n]
    int k = i >> 7, n = i & 127;
    W1t[(size_t)n * 128 + k] = (_Float16)W1[i];
  }
  if (i < 128 * 64) {   // W2t[n*128+k] = W2[k*64+n]
    int k = i >> 6, n = i & 63;
    W2t[(size_t)n * 128 + k] = (_Float16)W2[i];
  }
}

// Shadowed count: edge e ranks within shadow (e&3) of its col counter.
__global__ __launch_bounds__(256)
void count4_kernel(const int* __restrict__ col, int* __restrict__ cnt4,
                   int* __restrict__ eoff, int ne, int n) {
  int e = blockIdx.x * 256 + threadIdx.x;
  if (e < ne) eoff[e] = atomicAdd(&cnt4[(size_t)(e & 3) * n + col[e]], 1);
}

// Degree terms from 4 shadows + per-block partial sums + shadow prefix.
__global__ __launch_bounds__(256)
void partial_deg_kernel(const int* __restrict__ cnt4, int* __restrict__ cnt,
                        int4* __restrict__ sprefix, int* __restrict__ part,
                        float* __restrict__ dis, float* __restrict__ dinv, int n) {
  int i = blockIdx.x * 256 + threadIdx.x;
  int c0 = 0, c1 = 0, c2 = 0, c3 = 0;
  if (i < n) {
    c0 = cnt4[i];
    c1 = cnt4[(size_t)n + i];
    c2 = cnt4[(size_t)2 * n + i];
    c3 = cnt4[(size_t)3 * n + i];
  }
  int c = c0 + c1 + c2 + c3;
  if (i < n) {
    cnt[i] = c;
    sprefix[i] = make_int4(0, c0, c0 + c1, c0 + c1 + c2);
    float d = (float)(c + 1);   // +1 self loop
    dinv[i] = 1.0f / d;
    dis[i]  = rsqrtf(d);
  }
  int lane = threadIdx.x & 63, w = threadIdx.x >> 6;
  int s = c;
#pragma unroll
  for (int m = 32; m >= 1; m >>= 1) s += __shfl_xor(s, m, 64);
  __shared__ int wp[4];
  if (lane == 0) wp[w] = s;
  __syncthreads();
  if (threadIdx.x == 0) part[blockIdx.x] = wp[0] + wp[1] + wp[2] + wp[3];
}

__device__ inline int wave_incl_scan(int v, int lane) {
#pragma unroll
  for (int off = 1; off < 64; off <<= 1) {
    int u = __shfl_up(v, off, 64);
    if (lane >= off) v += u;
  }
  return v;
}

__global__ __launch_bounds__(256)
void scan_part_kernel(int* __restrict__ part, int nb) {
  int t = threadIdx.x;
  int v = (t < nb) ? part[t] : 0;
  int lane = t & 63, w = t >> 6;
  int inc = wave_incl_scan(v, lane);
  __shared__ int wp[4];
  if (lane == 63) wp[w] = inc;
  __syncthreads();
  if (t == 0) { int s = 0; for (int k = 0; k < 4; ++k) { int x = wp[k]; wp[k] = s; s += x; } }
  __syncthreads();
  int excl = wp[w] + inc - v;
  if (t < nb) part[t] = excl;
}

__global__ __launch_bounds__(256)
void scan_final_kernel(const int* __restrict__ cnt, const int* __restrict__ part,
                       int* __restrict__ row_ptr, int n) {
  int t = threadIdx.x;
  int i = blockIdx.x * 256 + t;
  int v = (i < n) ? cnt[i] : 0;
  int lane = t & 63, w = t >> 6;
  int inc = wave_incl_scan(v, lane);
  __shared__ int wp[4];
  if (lane == 63) wp[w] = inc;
  __syncthreads();
  if (t == 0) { int s = 0; for (int k = 0; k < 4; ++k) { int x = wp[k]; wp[k] = s; s += x; } }
  __syncthreads();
  int excl = part[blockIdx.x] + wp[w] + inc - v;
  if (i < n) {
    row_ptr[i] = excl;
    if (i == n - 1) row_ptr[n] = excl + v;
  }
}

// Slot = rowp[c] + shadow prefix + rank-within-shadow. No atomics.
__global__ __launch_bounds__(256)
void fill_kernel(const int* __restrict__ row, const int* __restrict__ col,
                 const int* __restrict__ eoff, const float* __restrict__ dis,
                 const int* __restrict__ row_ptr, const int4* __restrict__ sprefix,
                 int2* __restrict__ ep, int ne) {
  int e = blockIdx.x * 256 + threadIdx.x;
  if (e >= ne) return;
  int r = row[e], c = col[e];
  int4 sp = sprefix[c];
  int j = e & 3;
  int sb = (j == 0) ? sp.x : (j == 1) ? sp.y : (j == 2) ? sp.z : sp.w;
  int pos = row_ptr[c] + sb + eoff[e];
  float nrm = dis[r] * dis[c];
  ep[pos] = make_int2(r, __float_as_int(nrm));
}

// Y[N,M] = Xh[N,128] @ Wt^T (Wt is [M][128], fp16). MFMA 16x16x32.
template<int M>
__global__ __launch_bounds__(256)
void gemm_mfma_kernel(const _Float16* __restrict__ Xh,
                      const _Float16* __restrict__ Wt,
                      _Float16* __restrict__ Y, int N) {
  constexpr int K = 128;
  constexpr int CT = M / 16;
  const int t = threadIdx.x;
  const int lane = t & 63;
  const int i16 = lane & 15;
  const int quad = lane >> 4;
  const int row0 = blockIdx.x * 64 + (t >> 6) * 16;
  int arow = row0 + i16;
  if (arow >= N) arow = N - 1;
  const _Float16* aptr = Xh + (size_t)arow * K + quad * 8;
  floatx4 acc[CT];
#pragma unroll
  for (int c = 0; c < CT; ++c) acc[c] = (floatx4){0.f, 0.f, 0.f, 0.f};
#pragma unroll
  for (int k0 = 0; k0 < K; k0 += 32) {
    half8 a = *(const half8*)(aptr + k0);
#pragma unroll
    for (int c = 0; c < CT; ++c) {
      half8 b = *(const half8*)(Wt + (size_t)(c * 16 + i16) * K + quad * 8 + k0);
      acc[c] = __builtin_amdgcn_mfma_f32_16x16x32_f16(a, b, acc[c], 0, 0, 0);
    }
  }
#pragma unroll
  for (int c = 0; c < CT; ++c) {
#pragma unroll
    for (int r = 0; r < 4; ++r) {
      int gr = row0 + quad * 4 + r;
      if (gr < N) Y[(size_t)gr * M + c * 16 + i16] = (_Float16)acc[c][r];
    }
  }
}

// CH=128 aggregation: half-wave edge pairing (round-10, passing).
template<bool RELU>
__global__ __launch_bounds__(256)
void agg128h_kernel(const __half* __restrict__ xw, const int* __restrict__ row_ptr,
                    const int2* __restrict__ ep, const float* __restrict__ deg_inv,
                    const float* __restrict__ bias, __half* __restrict__ out, int n) {
  int wave = (blockIdx.x * 256 + threadIdx.x) >> 6;
  int lane = threadIdx.x & 63;
  if (wave >= n) return;
  const int node = wave;
  const int s0 = row_ptr[node], s1 = row_ptr[node + 1];
  const int sub = lane & 31;
  const bool lower = (lane < 32);
  floatx4 acc0 = {0.f, 0.f, 0.f, 0.f}, acc1 = {0.f, 0.f, 0.f, 0.f};
  for (int base = s0; base < s1; base += 64) {
    int m = s1 - base; if (m > 64) m = 64;
    int2 ed = make_int2(0, 0);
    if (lane < m) ed = ep[base + lane];
    for (int k = 0; k < m; k += 4) {
      {
        int   sa = __shfl(ed.x, k, 64);
        float wa = __int_as_float(__shfl(ed.y, k, 64));
        int sb = sa; float wb = 0.f;
        if (k + 1 < m) {
          sb = __shfl(ed.x, k + 1, 64);
          wb = __int_as_float(__shfl(ed.y, k + 1, 64));
        }
        int   s = lower ? sa : sb;
        float w = lower ? wa : wb;
        float2 raw = ((const float2*)(xw + (size_t)s * 128))[sub];
        const __half2* hp = (const __half2*)&raw;
        float2 lo = __half22float2(hp[0]);
        float2 hi = __half22float2(hp[1]);
        acc0[0] = fmaf(w, lo.x, acc0[0]); acc0[1] = fmaf(w, lo.y, acc0[1]);
        acc0[2] = fmaf(w, hi.x, acc0[2]); acc0[3] = fmaf(w, hi.y, acc0[3]);
      }
      if (k + 2 < m) {
        int   sa = __shfl(ed.x, k + 2, 64);
        float wa = __int_as_float(__shfl(ed.y, k + 2, 64));
        int sb = sa; float wb = 0.f;
        if (k + 3 < m) {
          sb = __shfl(ed.x, k + 3, 64);
          wb = __int_as_float(__shfl(ed.y, k + 3, 64));
        }
        int   s = lower ? sa : sb;
        float w = lower ? wa : wb;
        float2 raw = ((const float2*)(xw + (size_t)s * 128))[sub];
        const __half2* hp = (const __half2*)&raw;
        float2 lo = __half22float2(hp[0]);
        float2 hi = __half22float2(hp[1]);
        acc1[0] = fmaf(w, lo.x, acc1[0]); acc1[1] = fmaf(w, lo.y, acc1[1]);
        acc1[2] = fmaf(w, hi.x, acc1[2]); acc1[3] = fmaf(w, hi.y, acc1[3]);
      }
    }
  }
#pragma unroll
  for (int j = 0; j < 4; ++j) {
    acc0[j] += acc1[j];
    acc0[j] += __shfl_xor(acc0[j], 32, 64);
  }
  if (lower) {
    float di = deg_inv[node];
    float2 sraw = ((const float2*)(xw + (size_t)node * 128))[sub];
    const __half2* sp = (const __half2*)&sraw;
    float2 slo = __half22float2(sp[0]);
    float2 shi = __half22float2(sp[1]);
    float4 bv = ((const float4*)bias)[sub];
    float o0 = acc0[0] + slo.x * di + bv.x;
    float o1 = acc0[1] + slo.y * di + bv.y;
    float o2 = acc0[2] + shi.x * di + bv.z;
    float o3 = acc0[3] + shi.y * di + bv.w;
    if (RELU) {
      o0 = fmaxf(o0, 0.f); o1 = fmaxf(o1, 0.f);
      o2 = fmaxf(o2, 0.f); o3 = fmaxf(o3, 0.f);
    }
    __half2 h2[2];
    h2[0] = __float22half2_rn(make_float2(o0, o1));
    h2[1] = __float22half2_rn(make_float2(o2, o3));
    *(float2*)(out + (size_t)node * 128 + 4 * sub) = *(const float2*)h2;
  }
}

// CH=64 aggregation: half-wave edge pairing (round-10, passing).
template<bool RELU>
__global__ __launch_bounds__(256)
void agg64h_kernel(const __half* __restrict__ xw, const int* __restrict__ row_ptr,
                   const int2* __restrict__ ep, const float* __restrict__ deg_inv,
                   const float* __restrict__ bias, __half* __restrict__ out, int n) {
  int wave = (blockIdx.x * 256 + threadIdx.x) >> 6;
  int lane = threadIdx.x & 63;
  if (wave >= n) return;
  const int node = wave;
  const int s0 = row_ptr[node], s1 = row_ptr[node + 1];
  const int sub = lane & 31;
  const bool lower = (lane < 32);
  float2 acc0 = make_float2(0.f, 0.f), acc1 = make_float2(0.f, 0.f);
  for (int base = s0; base < s1; base += 64) {
    int m = s1 - base; if (m > 64) m = 64;
    int2 ed = make_int2(0, 0);
    if (lane < m) ed = ep[base + lane];
    for (int k = 0; k < m; k += 4) {
      {
        int   sa = __shfl(ed.x, k, 64);
        float wa = __int_as_float(__shfl(ed.y, k, 64));
        int sb = sa; float wb = 0.f;
        if (k + 1 < m) {
          sb = __shfl(ed.x, k + 1, 64);
          wb = __int_as_float(__shfl(ed.y, k + 1, 64));
        }
        int   s = lower ? sa : sb;
        float w = lower ? wa : wb;
        float2 v = __half22float2(((const __half2*)(xw + (size_t)s * 64))[sub]);
        acc0.x = fmaf(w, v.x, acc0.x); acc0.y = fmaf(w, v.y, acc0.y);
      }
      if (k + 2 < m) {
        int   sa = __shfl(ed.x, k + 2, 64);
        float wa = __int_as_float(__shfl(ed.y, k + 2, 64));
        int sb = sa; float wb = 0.f;
        if (k + 3 < m) {
          sb = __shfl(ed.x, k + 3, 64);
          wb = __int_as_float(__shfl(ed.y, k + 3, 64));
        }
        int   s = lower ? sa : sb;
        float w = lower ? wa : wb;
        float2 v = __half22float2(((const __half2*)(xw + (size_t)s * 64))[sub]);
        acc1.x = fmaf(w, v.x, acc1.x); acc1.y = fmaf(w, v.y, acc1.y);
      }
    }
  }
  acc0.x += acc1.x; acc0.y += acc1.y;
  acc0.x += __shfl_xor(acc0.x, 32, 64);
  acc0.y += __shfl_xor(acc0.y, 32, 64);
  if (lower) {
    float di = deg_inv[node];
    float2 sv = __half22float2(((const __half2*)(xw + (size_t)node * 64))[sub]);
    float2 bv = ((const float2*)bias)[sub];
    float ox = acc0.x + sv.x * di + bv.x;
    float oy = acc0.y + sv.y * di + bv.y;
    if (RELU) { ox = fmaxf(ox, 0.f); oy = fmaxf(oy, 0.f); }
    ((__half2*)(out + (size_t)node * 64))[sub] = __float22half2_rn(make_float2(ox, oy));
  }
}

// Decode: half-wave src/dst split (round-10, passing).
__global__ __launch_bounds__(256)
void decode_kernel(const __half* __restrict__ z, const int* __restrict__ eli,
                   float* __restrict__ out, int nl) {
  int wave = (blockIdx.x * 256 + threadIdx.x) >> 6;
  int lane = threadIdx.x & 63;
  if (wave >= nl) return;
  int src = eli[wave];
  int dst = eli[nl + wave];
  int node = (lane < 32) ? src : dst;
  int sub = lane & 31;
  float2 v = __half22float2(((const __half2*)(z + (size_t)node * 64))[sub]);
  float ox = __shfl_xor(v.x, 32, 64);
  float oy = __shfl_xor(v.y, 32, 64);
  float p = v.x * ox + v.y * oy;
#pragma unroll
  for (int m = 16; m >= 1; m >>= 1) p += __shfl_xor(p, m, 64);
  if (lane == 0) out[wave] = p;
}

extern "C" void kernel_launch(void* const* d_in, const int* in_sizes, int n_in,
                              void* d_out, int out_size, void* d_ws, size_t ws_size,
                              hipStream_t stream) {
  const float* x  = (const float*)d_in[0];
  const float* W1 = (const float*)d_in[1];
  const float* b1 = (const float*)d_in[2];
  const float* W2 = (const float*)d_in[3];
  const float* b2 = (const float*)d_in[4];
  const int* eidx = (const int*)d_in[5];
  const int* eli  = (const int*)d_in[6];
  const int N  = in_sizes[0] / 128;
  const int E  = in_sizes[5] / 2;
  const int NL = in_sizes[6] / 2;
  float* out = (float*)d_out;

  char* ws = (char*)d_ws;
  size_t off = 0;
  auto alloc = [&](size_t bytes) -> char* {
    char* p = ws + off;
    off = (off + bytes + 255) & ~(size_t)255;
    return p;
  };
  const int NB = (N + 255) / 256;
  float*    dis     = (float*)   alloc((size_t)N * 4);
  float*    dinv    = (float*)   alloc((size_t)N * 4);
  int*      cnt4    = (int*)     alloc((size_t)4 * N * 4);
  int*      cnt     = (int*)     alloc((size_t)N * 4);
  int4*     sprefix = (int4*)    alloc((size_t)N * 16);
  int*      rowp    = (int*)     alloc((size_t)(N + 1) * 4);
  int*      part    = (int*)     alloc((size_t)NB * 4);
  int*      eoff    = (int*)     alloc((size_t)E * 4);
  int2*     ep      = (int2*)    alloc((size_t)E * 8);
  _Float16* Xh      = (_Float16*)alloc((size_t)N * 128 * 2);
  _Float16* W1t     = (_Float16*)alloc((size_t)128 * 128 * 2);
  _Float16* W2t     = (_Float16*)alloc((size_t)64 * 128 * 2);
  __half*   bufA    = (__half*)  alloc((size_t)N * 128 * 2);
  __half*   bufB    = (__half*)  alloc((size_t)N * 128 * 2);
  __half*   bufC    = (__half*)  alloc((size_t)N * 64 * 2);
  __half*   z       = (__half*)  alloc((size_t)N * 64 * 2);
  (void)ws_size; (void)n_in; (void)out_size;

  const int* row = eidx;      // edge_index[0]
  const int* col = eidx + E;  // edge_index[1]

  hipMemsetAsync(cnt4, 0, (size_t)4 * N * 4, stream);
  const int n4 = N * 32;  // N*128/4 float4 groups
  prep_kernel<<<(n4 + 255) / 256, 256, 0, stream>>>(x, W1, W2, Xh, W1t, W2t, n4);
  count4_kernel<<<(E + 255) / 256, 256, 0, stream>>>(col, cnt4, eoff, E, N);
  partial_deg_kernel<<<NB, 256, 0, stream>>>(cnt4, cnt, sprefix, part, dis, dinv, N);
  scan_part_kernel<<<1, 256, 0, stream>>>(part, NB);
  scan_final_kernel<<<NB, 256, 0, stream>>>(cnt, part, rowp, N);
  fill_kernel<<<(E + 255) / 256, 256, 0, stream>>>(row, col, eoff, dis, rowp,
                                                   sprefix, ep, E);
  // conv1: bufA = half(Xh@W1); bufB = half(relu(agg(bufA)+dinv*bufA+b1))
  gemm_mfma_kernel<128><<<(N + 63) / 64, 256, 0, stream>>>(Xh, W1t, (_Float16*)bufA, N);
  agg128h_kernel<true><<<(N + 3) / 4, 256, 0, stream>>>(bufA, rowp, ep, dinv, b1, bufB, N);
  // conv2: bufC = half(bufB@W2); z = half(agg(bufC)+dinv*bufC+b2)
  gemm_mfma_kernel<64><<<(N + 63) / 64, 256, 0, stream>>>((const _Float16*)bufB, W2t,
                                                          (_Float16*)bufC, N);
  agg64h_kernel<false><<<(N + 3) / 4, 256, 0, stream>>>(bufC, rowp, ep, dinv, b2, z, N);
  // decode
  decode_kernel<<<(NL + 3) / 4, 256, 0, stream>>>(z, eli, out, NL);
}

// Round 12
// 265.401 us; speedup vs baseline: 1.0251x; 1.0251x over previous
//
#include <hip/hip_runtime.h>
#include <hip/hip_bf16.h>
#include <hip/hip_fp16.h>

// ---------------------------------------------------------------------------
// GCN link prediction (math fp32, fp16 tables, MFMA GEMMs):
//   prep | sort-based CSR build (NO global atomics):
//     hist(col>>8) -> base scan -> bucket scatter -> per-bucket csr ->
//     deg -> normfill
//   -> mfma gemm1 -> agg128 relu -> mfma gemm2 -> agg64 -> decode
// Round 12 = round-11 passing pipeline with the CSR-build subsystem replaced
// by a two-level bucket sort (device atomics eliminated; count pass was ~45us
// latency-bound on 800K atomic returns — shadowing proved contention wasn't
// the limiter). Buckets = col>>8, requires N <= 65536 (N=50000 here).
// ---------------------------------------------------------------------------

typedef _Float16 half8 __attribute__((ext_vector_type(8)));
typedef _Float16 half4v __attribute__((ext_vector_type(4)));
typedef float   floatx4 __attribute__((ext_vector_type(4)));

#define NBLK 256  // blocks for edge-chunk passes

// Convert x -> fp16 Xh; W1/W2 -> fp16 transposed (round-9 verbatim).
__global__ __launch_bounds__(256)
void prep_kernel(const float* __restrict__ x, const float* __restrict__ W1,
                 const float* __restrict__ W2, _Float16* __restrict__ Xh,
                 _Float16* __restrict__ W1t, _Float16* __restrict__ W2t, int n4) {
  int i = blockIdx.x * 256 + threadIdx.x;
  if (i < n4) {
    float4 v = ((const float4*)x)[i];
    half4v h; h[0] = (_Float16)v.x; h[1] = (_Float16)v.y;
    h[2] = (_Float16)v.z; h[3] = (_Float16)v.w;
    ((half4v*)Xh)[i] = h;
  }
  if (i < 128 * 128) {  // W1t[n*128+k] = W1[k*128+n]
    int k = i >> 7, n = i & 127;
    W1t[(size_t)n * 128 + k] = (_Float16)W1[i];
  }
  if (i < 128 * 64) {   // W2t[n*128+k] = W2[k*64+n]
    int k = i >> 6, n = i & 63;
    W2t[(size_t)n * 128 + k] = (_Float16)W2[i];
  }
}

// Pass A1: per-block LDS histogram of bucket = col>>8.
__global__ __launch_bounds__(256)
void hist_kernel(const int* __restrict__ col, int* __restrict__ bhist,
                 int ne, int chunk, int B) {
  __shared__ int h[256];
  int t = threadIdx.x, blk = blockIdx.x;
  for (int b = t; b < B; b += 256) h[b] = 0;
  __syncthreads();
  int e0 = blk * chunk, e1 = min(ne, e0 + chunk);
  for (int i = e0 + t; i < e1; i += 256)
    atomicAdd(&h[col[i] >> 8], 1);
  __syncthreads();
  for (int b = t; b < B; b += 256) bhist[blk * B + b] = h[b];
}

// Pass A2 (1 block): bucket totals, bucket starts bs[0..B], per-block bases.
__global__ __launch_bounds__(256)
void base_kernel(const int* __restrict__ bhist, int* __restrict__ base,
                 int* __restrict__ bs, int B) {
  __shared__ int tot[256];
  __shared__ int start[257];
  int t = threadIdx.x;
  if (t < B) {
    int s = 0;
    for (int blk = 0; blk < NBLK; ++blk) s += bhist[blk * B + t];
    tot[t] = s;
  }
  __syncthreads();
  if (t == 0) {
    int run = 0;
    for (int b = 0; b < B; ++b) { start[b] = run; run += tot[b]; }
    start[B] = run;
  }
  __syncthreads();
  if (t <= B) bs[t] = start[t];
  if (t < B) {
    int run = start[t];
    for (int blk = 0; blk < NBLK; ++blk) {
      base[blk * B + t] = run;
      run += bhist[blk * B + t];
    }
  }
}

// Pass A3: scatter edges into bucket-grouped tmp[(r,c)] via LDS cursors.
__global__ __launch_bounds__(256)
void bucket_scatter_kernel(const int* __restrict__ row, const int* __restrict__ col,
                           const int* __restrict__ base, int2* __restrict__ tmp,
                           int ne, int chunk, int B) {
  __shared__ int cur[256];
  int t = threadIdx.x, blk = blockIdx.x;
  for (int b = t; b < B; b += 256) cur[b] = base[blk * B + b];
  __syncthreads();
  int e0 = blk * chunk, e1 = min(ne, e0 + chunk);
  for (int i = e0 + t; i < e1; i += 256) {
    int c = col[i];
    int pos = atomicAdd(&cur[c >> 8], 1);
    tmp[pos] = make_int2(row[i], c);
  }
}

// Pass B1 (one block per bucket): 256-bin LDS histogram over col&255 ->
// cnt, rowp, and each edge's final CSR position epos (LDS cursors).
__global__ __launch_bounds__(256)
void bucket_csr_kernel(const int2* __restrict__ tmp, const int* __restrict__ bs,
                       int* __restrict__ cnt, int* __restrict__ rowp,
                       int* __restrict__ epos, int n) {
  __shared__ int h[256], lo[256], cur[256];
  int t = threadIdx.x, b = blockIdx.x;
  h[t] = 0;
  __syncthreads();
  int s0 = bs[b], s1 = bs[b + 1];
  for (int i = s0 + t; i < s1; i += 256)
    atomicAdd(&h[tmp[i].y & 255], 1);
  __syncthreads();
  if (t == 0) {
    int run = 0;
    for (int cb = 0; cb < 256; ++cb) { lo[cb] = run; run += h[cb]; }
  }
  __syncthreads();
  cur[t] = lo[t];
  int node = (b << 8) + t;
  if (node < n) {
    cnt[node] = h[t];
    rowp[node] = s0 + lo[t];
    if (node == n - 1) rowp[n] = s1;   // last bucket end == E
  }
  __syncthreads();
  for (int i = s0 + t; i < s1; i += 256) {
    int cb = tmp[i].y & 255;
    int r = atomicAdd(&cur[cb], 1);
    epos[i] = s0 + r;
  }
}

// Degree terms (elementwise, no atomics).
__global__ __launch_bounds__(256)
void deg_kernel(const int* __restrict__ cnt, float* __restrict__ dis,
                float* __restrict__ dinv, int n) {
  int i = blockIdx.x * 256 + threadIdx.x;
  if (i < n) {
    float d = (float)(cnt[i] + 1);   // +1 self loop
    dinv[i] = 1.0f / d;
    dis[i]  = rsqrtf(d);
  }
}

// Pass B2: finalize ep[pos] = (r, dis[r]*dis[c]). No atomics.
__global__ __launch_bounds__(256)
void normfill_kernel(const int2* __restrict__ tmp, const int* __restrict__ epos,
                     const float* __restrict__ dis, int2* __restrict__ ep, int ne) {
  int e = blockIdx.x * 256 + threadIdx.x;
  if (e >= ne) return;
  int2 rc = tmp[e];
  float nrm = dis[rc.x] * dis[rc.y];
  ep[epos[e]] = make_int2(rc.x, __float_as_int(nrm));
}

// Y[N,M] = Xh[N,128] @ Wt^T (Wt is [M][128], fp16). MFMA 16x16x32.
template<int M>
__global__ __launch_bounds__(256)
void gemm_mfma_kernel(const _Float16* __restrict__ Xh,
                      const _Float16* __restrict__ Wt,
                      _Float16* __restrict__ Y, int N) {
  constexpr int K = 128;
  constexpr int CT = M / 16;
  const int t = threadIdx.x;
  const int lane = t & 63;
  const int i16 = lane & 15;
  const int quad = lane >> 4;
  const int row0 = blockIdx.x * 64 + (t >> 6) * 16;
  int arow = row0 + i16;
  if (arow >= N) arow = N - 1;
  const _Float16* aptr = Xh + (size_t)arow * K + quad * 8;
  floatx4 acc[CT];
#pragma unroll
  for (int c = 0; c < CT; ++c) acc[c] = (floatx4){0.f, 0.f, 0.f, 0.f};
#pragma unroll
  for (int k0 = 0; k0 < K; k0 += 32) {
    half8 a = *(const half8*)(aptr + k0);
#pragma unroll
    for (int c = 0; c < CT; ++c) {
      half8 b = *(const half8*)(Wt + (size_t)(c * 16 + i16) * K + quad * 8 + k0);
      acc[c] = __builtin_amdgcn_mfma_f32_16x16x32_f16(a, b, acc[c], 0, 0, 0);
    }
  }
#pragma unroll
  for (int c = 0; c < CT; ++c) {
#pragma unroll
    for (int r = 0; r < 4; ++r) {
      int gr = row0 + quad * 4 + r;
      if (gr < N) Y[(size_t)gr * M + c * 16 + i16] = (_Float16)acc[c][r];
    }
  }
}

// CH=128 aggregation: half-wave edge pairing (round-10, passing).
template<bool RELU>
__global__ __launch_bounds__(256)
void agg128h_kernel(const __half* __restrict__ xw, const int* __restrict__ row_ptr,
                    const int2* __restrict__ ep, const float* __restrict__ deg_inv,
                    const float* __restrict__ bias, __half* __restrict__ out, int n) {
  int wave = (blockIdx.x * 256 + threadIdx.x) >> 6;
  int lane = threadIdx.x & 63;
  if (wave >= n) return;
  const int node = wave;
  const int s0 = row_ptr[node], s1 = row_ptr[node + 1];
  const int sub = lane & 31;
  const bool lower = (lane < 32);
  floatx4 acc0 = {0.f, 0.f, 0.f, 0.f}, acc1 = {0.f, 0.f, 0.f, 0.f};
  for (int base = s0; base < s1; base += 64) {
    int m = s1 - base; if (m > 64) m = 64;
    int2 ed = make_int2(0, 0);
    if (lane < m) ed = ep[base + lane];
    for (int k = 0; k < m; k += 4) {
      {
        int   sa = __shfl(ed.x, k, 64);
        float wa = __int_as_float(__shfl(ed.y, k, 64));
        int sb = sa; float wb = 0.f;
        if (k + 1 < m) {
          sb = __shfl(ed.x, k + 1, 64);
          wb = __int_as_float(__shfl(ed.y, k + 1, 64));
        }
        int   s = lower ? sa : sb;
        float w = lower ? wa : wb;
        float2 raw = ((const float2*)(xw + (size_t)s * 128))[sub];
        const __half2* hp = (const __half2*)&raw;
        float2 lo = __half22float2(hp[0]);
        float2 hi = __half22float2(hp[1]);
        acc0[0] = fmaf(w, lo.x, acc0[0]); acc0[1] = fmaf(w, lo.y, acc0[1]);
        acc0[2] = fmaf(w, hi.x, acc0[2]); acc0[3] = fmaf(w, hi.y, acc0[3]);
      }
      if (k + 2 < m) {
        int   sa = __shfl(ed.x, k + 2, 64);
        float wa = __int_as_float(__shfl(ed.y, k + 2, 64));
        int sb = sa; float wb = 0.f;
        if (k + 3 < m) {
          sb = __shfl(ed.x, k + 3, 64);
          wb = __int_as_float(__shfl(ed.y, k + 3, 64));
        }
        int   s = lower ? sa : sb;
        float w = lower ? wa : wb;
        float2 raw = ((const float2*)(xw + (size_t)s * 128))[sub];
        const __half2* hp = (const __half2*)&raw;
        float2 lo = __half22float2(hp[0]);
        float2 hi = __half22float2(hp[1]);
        acc1[0] = fmaf(w, lo.x, acc1[0]); acc1[1] = fmaf(w, lo.y, acc1[1]);
        acc1[2] = fmaf(w, hi.x, acc1[2]); acc1[3] = fmaf(w, hi.y, acc1[3]);
      }
    }
  }
#pragma unroll
  for (int j = 0; j < 4; ++j) {
    acc0[j] += acc1[j];
    acc0[j] += __shfl_xor(acc0[j], 32, 64);
  }
  if (lower) {
    float di = deg_inv[node];
    float2 sraw = ((const float2*)(xw + (size_t)node * 128))[sub];
    const __half2* sp = (const __half2*)&sraw;
    float2 slo = __half22float2(sp[0]);
    float2 shi = __half22float2(sp[1]);
    float4 bv = ((const float4*)bias)[sub];
    float o0 = acc0[0] + slo.x * di + bv.x;
    float o1 = acc0[1] + slo.y * di + bv.y;
    float o2 = acc0[2] + shi.x * di + bv.z;
    float o3 = acc0[3] + shi.y * di + bv.w;
    if (RELU) {
      o0 = fmaxf(o0, 0.f); o1 = fmaxf(o1, 0.f);
      o2 = fmaxf(o2, 0.f); o3 = fmaxf(o3, 0.f);
    }
    __half2 h2[2];
    h2[0] = __float22half2_rn(make_float2(o0, o1));
    h2[1] = __float22half2_rn(make_float2(o2, o3));
    *(float2*)(out + (size_t)node * 128 + 4 * sub) = *(const float2*)h2;
  }
}

// CH=64 aggregation: half-wave edge pairing (round-10, passing).
template<bool RELU>
__global__ __launch_bounds__(256)
void agg64h_kernel(const __half* __restrict__ xw, const int* __restrict__ row_ptr,
                   const int2* __restrict__ ep, const float* __restrict__ deg_inv,
                   const float* __restrict__ bias, __half* __restrict__ out, int n) {
  int wave = (blockIdx.x * 256 + threadIdx.x) >> 6;
  int lane = threadIdx.x & 63;
  if (wave >= n) return;
  const int node = wave;
  const int s0 = row_ptr[node], s1 = row_ptr[node + 1];
  const int sub = lane & 31;
  const bool lower = (lane < 32);
  float2 acc0 = make_float2(0.f, 0.f), acc1 = make_float2(0.f, 0.f);
  for (int base = s0; base < s1; base += 64) {
    int m = s1 - base; if (m > 64) m = 64;
    int2 ed = make_int2(0, 0);
    if (lane < m) ed = ep[base + lane];
    for (int k = 0; k < m; k += 4) {
      {
        int   sa = __shfl(ed.x, k, 64);
        float wa = __int_as_float(__shfl(ed.y, k, 64));
        int sb = sa; float wb = 0.f;
        if (k + 1 < m) {
          sb = __shfl(ed.x, k + 1, 64);
          wb = __int_as_float(__shfl(ed.y, k + 1, 64));
        }
        int   s = lower ? sa : sb;
        float w = lower ? wa : wb;
        float2 v = __half22float2(((const __half2*)(xw + (size_t)s * 64))[sub]);
        acc0.x = fmaf(w, v.x, acc0.x); acc0.y = fmaf(w, v.y, acc0.y);
      }
      if (k + 2 < m) {
        int   sa = __shfl(ed.x, k + 2, 64);
        float wa = __int_as_float(__shfl(ed.y, k + 2, 64));
        int sb = sa; float wb = 0.f;
        if (k + 3 < m) {
          sb = __shfl(ed.x, k + 3, 64);
          wb = __int_as_float(__shfl(ed.y, k + 3, 64));
        }
        int   s = lower ? sa : sb;
        float w = lower ? wa : wb;
        float2 v = __half22float2(((const __half2*)(xw + (size_t)s * 64))[sub]);
        acc1.x = fmaf(w, v.x, acc1.x); acc1.y = fmaf(w, v.y, acc1.y);
      }
    }
  }
  acc0.x += acc1.x; acc0.y += acc1.y;
  acc0.x += __shfl_xor(acc0.x, 32, 64);
  acc0.y += __shfl_xor(acc0.y, 32, 64);
  if (lower) {
    float di = deg_inv[node];
    float2 sv = __half22float2(((const __half2*)(xw + (size_t)node * 64))[sub]);
    float2 bv = ((const float2*)bias)[sub];
    float ox = acc0.x + sv.x * di + bv.x;
    float oy = acc0.y + sv.y * di + bv.y;
    if (RELU) { ox = fmaxf(ox, 0.f); oy = fmaxf(oy, 0.f); }
    ((__half2*)(out + (size_t)node * 64))[sub] = __float22half2_rn(make_float2(ox, oy));
  }
}

// Decode: half-wave src/dst split (round-10, passing).
__global__ __launch_bounds__(256)
void decode_kernel(const __half* __restrict__ z, const int* __restrict__ eli,
                   float* __restrict__ out, int nl) {
  int wave = (blockIdx.x * 256 + threadIdx.x) >> 6;
  int lane = threadIdx.x & 63;
  if (wave >= nl) return;
  int src = eli[wave];
  int dst = eli[nl + wave];
  int node = (lane < 32) ? src : dst;
  int sub = lane & 31;
  float2 v = __half22float2(((const __half2*)(z + (size_t)node * 64))[sub]);
  float ox = __shfl_xor(v.x, 32, 64);
  float oy = __shfl_xor(v.y, 32, 64);
  float p = v.x * ox + v.y * oy;
#pragma unroll
  for (int m = 16; m >= 1; m >>= 1) p += __shfl_xor(p, m, 64);
  if (lane == 0) out[wave] = p;
}

extern "C" void kernel_launch(void* const* d_in, const int* in_sizes, int n_in,
                              void* d_out, int out_size, void* d_ws, size_t ws_size,
                              hipStream_t stream) {
  const float* x  = (const float*)d_in[0];
  const float* W1 = (const float*)d_in[1];
  const float* b1 = (const float*)d_in[2];
  const float* W2 = (const float*)d_in[3];
  const float* b2 = (const float*)d_in[4];
  const int* eidx = (const int*)d_in[5];
  const int* eli  = (const int*)d_in[6];
  const int N  = in_sizes[0] / 128;
  const int E  = in_sizes[5] / 2;
  const int NL = in_sizes[6] / 2;
  float* out = (float*)d_out;

  char* ws = (char*)d_ws;
  size_t off = 0;
  auto alloc = [&](size_t bytes) -> char* {
    char* p = ws + off;
    off = (off + bytes + 255) & ~(size_t)255;
    return p;
  };
  const int B = (N + 255) / 256;        // buckets (col>>8); needs N <= 65536
  const int chunk = (E + NBLK - 1) / NBLK;
  float*    dis   = (float*)   alloc((size_t)N * 4);
  float*    dinv  = (float*)   alloc((size_t)N * 4);
  int*      cnt   = (int*)     alloc((size_t)N * 4);
  int*      rowp  = (int*)     alloc((size_t)(N + 1) * 4);
  int*      bhist = (int*)     alloc((size_t)NBLK * B * 4);
  int*      base  = (int*)     alloc((size_t)NBLK * B * 4);
  int*      bs    = (int*)     alloc((size_t)(B + 1) * 4);
  int2*     tmp   = (int2*)    alloc((size_t)E * 8);
  int*      epos  = (int*)     alloc((size_t)E * 4);
  int2*     ep    = (int2*)    alloc((size_t)E * 8);
  _Float16* Xh    = (_Float16*)alloc((size_t)N * 128 * 2);
  _Float16* W1t   = (_Float16*)alloc((size_t)128 * 128 * 2);
  _Float16* W2t   = (_Float16*)alloc((size_t)64 * 128 * 2);
  __half*   bufA  = (__half*)  alloc((size_t)N * 128 * 2);
  __half*   bufB  = (__half*)  alloc((size_t)N * 128 * 2);
  __half*   bufC  = (__half*)  alloc((size_t)N * 64 * 2);
  __half*   z     = (__half*)  alloc((size_t)N * 64 * 2);
  (void)ws_size; (void)n_in; (void)out_size;

  const int* row = eidx;      // edge_index[0]
  const int* col = eidx + E;  // edge_index[1]

  const int n4 = N * 32;  // N*128/4 float4 groups
  prep_kernel<<<(n4 + 255) / 256, 256, 0, stream>>>(x, W1, W2, Xh, W1t, W2t, n4);
  // sort-based CSR build (no global atomics)
  hist_kernel<<<NBLK, 256, 0, stream>>>(col, bhist, E, chunk, B);
  base_kernel<<<1, 256, 0, stream>>>(bhist, base, bs, B);
  bucket_scatter_kernel<<<NBLK, 256, 0, stream>>>(row, col, base, tmp, E, chunk, B);
  bucket_csr_kernel<<<B, 256, 0, stream>>>(tmp, bs, cnt, rowp, epos, N);
  deg_kernel<<<(N + 255) / 256, 256, 0, stream>>>(cnt, dis, dinv, N);
  normfill_kernel<<<(E + 255) / 256, 256, 0, stream>>>(tmp, epos, dis, ep, E);
  // conv1: bufA = half(Xh@W1); bufB = half(relu(agg(bufA)+dinv*bufA+b1))
  gemm_mfma_kernel<128><<<(N + 63) / 64, 256, 0, stream>>>(Xh, W1t, (_Float16*)bufA, N);
  agg128h_kernel<true><<<(N + 3) / 4, 256, 0, stream>>>(bufA, rowp, ep, dinv, b1, bufB, N);
  // conv2: bufC = half(bufB@W2); z = half(agg(bufC)+dinv*bufC+b2)
  gemm_mfma_kernel<64><<<(N + 63) / 64, 256, 0, stream>>>((const _Float16*)bufB, W2t,
                                                          (_Float16*)bufC, N);
  agg64h_kernel<false><<<(N + 3) / 4, 256, 0, stream>>>(bufC, rowp, ep, dinv, b2, z, N);
  // decode
  decode_kernel<<<(NL + 3) / 4, 256, 0, stream>>>(z, eli, out, NL);
}

// Round 13
// 261.211 us; speedup vs baseline: 1.0415x; 1.0160x over previous
//
#include <hip/hip_runtime.h>
#include <hip/hip_bf16.h>
#include <hip/hip_fp16.h>

// ---------------------------------------------------------------------------
// GCN link prediction (math fp32, fp16 tables, MFMA GEMMs):
//   prep | sort-based CSR build (NO global atomics, slim edge pipeline):
//     hist(col>>8) -> base scan -> bucket scatter -> bucket csr
//       (writes ep[pos]=src, cnt, rowp, dis, dinv)
//   -> mfma gemm1 -> agg128 relu -> mfma gemm2 -> agg64 -> decode
// Round 13 = round-12 passing pipeline with the edge pipeline slimmed:
// ep stores src only (4B/edge); norm = dis[src]*dis[node] computed in agg
// (same fp32 ops, same order -> bit-identical); normfill/deg kernels deleted.
// 10 launches (was 13).
// ---------------------------------------------------------------------------

typedef _Float16 half8 __attribute__((ext_vector_type(8)));
typedef _Float16 half4v __attribute__((ext_vector_type(4)));
typedef float   floatx4 __attribute__((ext_vector_type(4)));

#define NBLK 256  // blocks for edge-chunk passes

// Convert x -> fp16 Xh; W1/W2 -> fp16 transposed (round-9 verbatim).
__global__ __launch_bounds__(256)
void prep_kernel(const float* __restrict__ x, const float* __restrict__ W1,
                 const float* __restrict__ W2, _Float16* __restrict__ Xh,
                 _Float16* __restrict__ W1t, _Float16* __restrict__ W2t, int n4) {
  int i = blockIdx.x * 256 + threadIdx.x;
  if (i < n4) {
    float4 v = ((const float4*)x)[i];
    half4v h; h[0] = (_Float16)v.x; h[1] = (_Float16)v.y;
    h[2] = (_Float16)v.z; h[3] = (_Float16)v.w;
    ((half4v*)Xh)[i] = h;
  }
  if (i < 128 * 128) {  // W1t[n*128+k] = W1[k*128+n]
    int k = i >> 7, n = i & 127;
    W1t[(size_t)n * 128 + k] = (_Float16)W1[i];
  }
  if (i < 128 * 64) {   // W2t[n*128+k] = W2[k*64+n]
    int k = i >> 6, n = i & 63;
    W2t[(size_t)n * 128 + k] = (_Float16)W2[i];
  }
}

// Pass A1: per-block LDS histogram of bucket = col>>8.
__global__ __launch_bounds__(256)
void hist_kernel(const int* __restrict__ col, int* __restrict__ bhist,
                 int ne, int chunk, int B) {
  __shared__ int h[256];
  int t = threadIdx.x, blk = blockIdx.x;
  for (int b = t; b < B; b += 256) h[b] = 0;
  __syncthreads();
  int e0 = blk * chunk, e1 = min(ne, e0 + chunk);
  for (int i = e0 + t; i < e1; i += 256)
    atomicAdd(&h[col[i] >> 8], 1);
  __syncthreads();
  for (int b = t; b < B; b += 256) bhist[blk * B + b] = h[b];
}

// Pass A2 (1 block): bucket totals, bucket starts bs[0..B], per-block bases.
__global__ __launch_bounds__(256)
void base_kernel(const int* __restrict__ bhist, int* __restrict__ base,
                 int* __restrict__ bs, int B) {
  __shared__ int tot[256];
  __shared__ int start[257];
  int t = threadIdx.x;
  if (t < B) {
    int s = 0;
    for (int blk = 0; blk < NBLK; ++blk) s += bhist[blk * B + t];
    tot[t] = s;
  }
  __syncthreads();
  if (t == 0) {
    int run = 0;
    for (int b = 0; b < B; ++b) { start[b] = run; run += tot[b]; }
    start[B] = run;
  }
  __syncthreads();
  if (t <= B) bs[t] = start[t];
  if (t < B) {
    int run = start[t];
    for (int blk = 0; blk < NBLK; ++blk) {
      base[blk * B + t] = run;
      run += bhist[blk * B + t];
    }
  }
}

// Pass A3: scatter edges into bucket-grouped tmp[(r,c)] via LDS cursors.
__global__ __launch_bounds__(256)
void bucket_scatter_kernel(const int* __restrict__ row, const int* __restrict__ col,
                           const int* __restrict__ base, int2* __restrict__ tmp,
                           int ne, int chunk, int B) {
  __shared__ int cur[256];
  int t = threadIdx.x, blk = blockIdx.x;
  for (int b = t; b < B; b += 256) cur[b] = base[blk * B + b];
  __syncthreads();
  int e0 = blk * chunk, e1 = min(ne, e0 + chunk);
  for (int i = e0 + t; i < e1; i += 256) {
    int c = col[i];
    int pos = atomicAdd(&cur[c >> 8], 1);
    tmp[pos] = make_int2(row[i], c);
  }
}

// Pass B1 (one block per bucket): 256-bin LDS histogram over col&255 ->
// cnt, rowp, dis, dinv, and final CSR scatter ep[pos] = src (LDS cursors).
__global__ __launch_bounds__(256)
void bucket_csr_kernel(const int2* __restrict__ tmp, const int* __restrict__ bs,
                       int* __restrict__ cnt, int* __restrict__ rowp,
                       float* __restrict__ dis, float* __restrict__ dinv,
                       int* __restrict__ ep, int n) {
  __shared__ int h[256], lo[256], cur[256];
  int t = threadIdx.x, b = blockIdx.x;
  h[t] = 0;
  __syncthreads();
  int s0 = bs[b], s1 = bs[b + 1];
  for (int i = s0 + t; i < s1; i += 256)
    atomicAdd(&h[tmp[i].y & 255], 1);
  __syncthreads();
  if (t == 0) {
    int run = 0;
    for (int cb = 0; cb < 256; ++cb) { lo[cb] = run; run += h[cb]; }
  }
  __syncthreads();
  cur[t] = lo[t];
  int node = (b << 8) + t;
  if (node < n) {
    int c = h[t];
    cnt[node] = c;
    rowp[node] = s0 + lo[t];
    float d = (float)(c + 1);   // +1 self loop
    dinv[node] = 1.0f / d;
    dis[node]  = rsqrtf(d);
    if (node == n - 1) rowp[n] = s1;   // last bucket end == E
  }
  __syncthreads();
  for (int i = s0 + t; i < s1; i += 256) {
    int2 rc = tmp[i];
    int r = atomicAdd(&cur[rc.y & 255], 1);
    ep[s0 + r] = rc.x;
  }
}

// Y[N,M] = Xh[N,128] @ Wt^T (Wt is [M][128], fp16). MFMA 16x16x32.
template<int M>
__global__ __launch_bounds__(256)
void gemm_mfma_kernel(const _Float16* __restrict__ Xh,
                      const _Float16* __restrict__ Wt,
                      _Float16* __restrict__ Y, int N) {
  constexpr int K = 128;
  constexpr int CT = M / 16;
  const int t = threadIdx.x;
  const int lane = t & 63;
  const int i16 = lane & 15;
  const int quad = lane >> 4;
  const int row0 = blockIdx.x * 64 + (t >> 6) * 16;
  int arow = row0 + i16;
  if (arow >= N) arow = N - 1;
  const _Float16* aptr = Xh + (size_t)arow * K + quad * 8;
  floatx4 acc[CT];
#pragma unroll
  for (int c = 0; c < CT; ++c) acc[c] = (floatx4){0.f, 0.f, 0.f, 0.f};
#pragma unroll
  for (int k0 = 0; k0 < K; k0 += 32) {
    half8 a = *(const half8*)(aptr + k0);
#pragma unroll
    for (int c = 0; c < CT; ++c) {
      half8 b = *(const half8*)(Wt + (size_t)(c * 16 + i16) * K + quad * 8 + k0);
      acc[c] = __builtin_amdgcn_mfma_f32_16x16x32_f16(a, b, acc[c], 0, 0, 0);
    }
  }
#pragma unroll
  for (int c = 0; c < CT; ++c) {
#pragma unroll
    for (int r = 0; r < 4; ++r) {
      int gr = row0 + quad * 4 + r;
      if (gr < N) Y[(size_t)gr * M + c * 16 + i16] = (_Float16)acc[c][r];
    }
  }
}

// CH=128 aggregation: half-wave edge pairing; ep = src only, per-lane dis[src]
// gather, w = dis[src]*dis[node] (same fp32 ops/order as old normfill path).
template<bool RELU>
__global__ __launch_bounds__(256)
void agg128h_kernel(const __half* __restrict__ xw, const int* __restrict__ row_ptr,
                    const int* __restrict__ ep, const float* __restrict__ dis,
                    const float* __restrict__ deg_inv, const float* __restrict__ bias,
                    __half* __restrict__ out, int n) {
  int wave = (blockIdx.x * 256 + threadIdx.x) >> 6;
  int lane = threadIdx.x & 63;
  if (wave >= n) return;
  const int node = wave;
  const int s0 = row_ptr[node], s1 = row_ptr[node + 1];
  const int sub = lane & 31;
  const bool lower = (lane < 32);
  const float disc = dis[node];
  floatx4 acc0 = {0.f, 0.f, 0.f, 0.f}, acc1 = {0.f, 0.f, 0.f, 0.f};
  for (int base = s0; base < s1; base += 64) {
    int m = s1 - base; if (m > 64) m = 64;
    int er = 0; float dr = 0.f;
    if (lane < m) { er = ep[base + lane]; dr = dis[er]; }
    for (int k = 0; k < m; k += 4) {
      {
        int   sa = __shfl(er, k, 64);
        float da = __shfl(dr, k, 64);
        int sb = sa; float db = 0.f;
        if (k + 1 < m) {
          sb = __shfl(er, k + 1, 64);
          db = __shfl(dr, k + 1, 64);
        }
        int   s = lower ? sa : sb;
        float w = (lower ? da : db) * disc;
        float2 raw = ((const float2*)(xw + (size_t)s * 128))[sub];
        const __half2* hp = (const __half2*)&raw;
        float2 lo = __half22float2(hp[0]);
        float2 hi = __half22float2(hp[1]);
        acc0[0] = fmaf(w, lo.x, acc0[0]); acc0[1] = fmaf(w, lo.y, acc0[1]);
        acc0[2] = fmaf(w, hi.x, acc0[2]); acc0[3] = fmaf(w, hi.y, acc0[3]);
      }
      if (k + 2 < m) {
        int   sa = __shfl(er, k + 2, 64);
        float da = __shfl(dr, k + 2, 64);
        int sb = sa; float db = 0.f;
        if (k + 3 < m) {
          sb = __shfl(er, k + 3, 64);
          db = __shfl(dr, k + 3, 64);
        }
        int   s = lower ? sa : sb;
        float w = (lower ? da : db) * disc;
        float2 raw = ((const float2*)(xw + (size_t)s * 128))[sub];
        const __half2* hp = (const __half2*)&raw;
        float2 lo = __half22float2(hp[0]);
        float2 hi = __half22float2(hp[1]);
        acc1[0] = fmaf(w, lo.x, acc1[0]); acc1[1] = fmaf(w, lo.y, acc1[1]);
        acc1[2] = fmaf(w, hi.x, acc1[2]); acc1[3] = fmaf(w, hi.y, acc1[3]);
      }
    }
  }
#pragma unroll
  for (int j = 0; j < 4; ++j) {
    acc0[j] += acc1[j];
    acc0[j] += __shfl_xor(acc0[j], 32, 64);
  }
  if (lower) {
    float di = deg_inv[node];
    float2 sraw = ((const float2*)(xw + (size_t)node * 128))[sub];
    const __half2* sp = (const __half2*)&sraw;
    float2 slo = __half22float2(sp[0]);
    float2 shi = __half22float2(sp[1]);
    float4 bv = ((const float4*)bias)[sub];
    float o0 = acc0[0] + slo.x * di + bv.x;
    float o1 = acc0[1] + slo.y * di + bv.y;
    float o2 = acc0[2] + shi.x * di + bv.z;
    float o3 = acc0[3] + shi.y * di + bv.w;
    if (RELU) {
      o0 = fmaxf(o0, 0.f); o1 = fmaxf(o1, 0.f);
      o2 = fmaxf(o2, 0.f); o3 = fmaxf(o3, 0.f);
    }
    __half2 h2[2];
    h2[0] = __float22half2_rn(make_float2(o0, o1));
    h2[1] = __float22half2_rn(make_float2(o2, o3));
    *(float2*)(out + (size_t)node * 128 + 4 * sub) = *(const float2*)h2;
  }
}

// CH=64 aggregation: same slim-edge scheme.
template<bool RELU>
__global__ __launch_bounds__(256)
void agg64h_kernel(const __half* __restrict__ xw, const int* __restrict__ row_ptr,
                   const int* __restrict__ ep, const float* __restrict__ dis,
                   const float* __restrict__ deg_inv, const float* __restrict__ bias,
                   __half* __restrict__ out, int n) {
  int wave = (blockIdx.x * 256 + threadIdx.x) >> 6;
  int lane = threadIdx.x & 63;
  if (wave >= n) return;
  const int node = wave;
  const int s0 = row_ptr[node], s1 = row_ptr[node + 1];
  const int sub = lane & 31;
  const bool lower = (lane < 32);
  const float disc = dis[node];
  float2 acc0 = make_float2(0.f, 0.f), acc1 = make_float2(0.f, 0.f);
  for (int base = s0; base < s1; base += 64) {
    int m = s1 - base; if (m > 64) m = 64;
    int er = 0; float dr = 0.f;
    if (lane < m) { er = ep[base + lane]; dr = dis[er]; }
    for (int k = 0; k < m; k += 4) {
      {
        int   sa = __shfl(er, k, 64);
        float da = __shfl(dr, k, 64);
        int sb = sa; float db = 0.f;
        if (k + 1 < m) {
          sb = __shfl(er, k + 1, 64);
          db = __shfl(dr, k + 1, 64);
        }
        int   s = lower ? sa : sb;
        float w = (lower ? da : db) * disc;
        float2 v = __half22float2(((const __half2*)(xw + (size_t)s * 64))[sub]);
        acc0.x = fmaf(w, v.x, acc0.x); acc0.y = fmaf(w, v.y, acc0.y);
      }
      if (k + 2 < m) {
        int   sa = __shfl(er, k + 2, 64);
        float da = __shfl(dr, k + 2, 64);
        int sb = sa; float db = 0.f;
        if (k + 3 < m) {
          sb = __shfl(er, k + 3, 64);
          db = __shfl(dr, k + 3, 64);
        }
        int   s = lower ? sa : sb;
        float w = (lower ? da : db) * disc;
        float2 v = __half22float2(((const __half2*)(xw + (size_t)s * 64))[sub]);
        acc1.x = fmaf(w, v.x, acc1.x); acc1.y = fmaf(w, v.y, acc1.y);
      }
    }
  }
  acc0.x += acc1.x; acc0.y += acc1.y;
  acc0.x += __shfl_xor(acc0.x, 32, 64);
  acc0.y += __shfl_xor(acc0.y, 32, 64);
  if (lower) {
    float di = deg_inv[node];
    float2 sv = __half22float2(((const __half2*)(xw + (size_t)node * 64))[sub]);
    float2 bv = ((const float2*)bias)[sub];
    float ox = acc0.x + sv.x * di + bv.x;
    float oy = acc0.y + sv.y * di + bv.y;
    if (RELU) { ox = fmaxf(ox, 0.f); oy = fmaxf(oy, 0.f); }
    ((__half2*)(out + (size_t)node * 64))[sub] = __float22half2_rn(make_float2(ox, oy));
  }
}

// Decode: half-wave src/dst split (round-10, passing).
__global__ __launch_bounds__(256)
void decode_kernel(const __half* __restrict__ z, const int* __restrict__ eli,
                   float* __restrict__ out, int nl) {
  int wave = (blockIdx.x * 256 + threadIdx.x) >> 6;
  int lane = threadIdx.x & 63;
  if (wave >= nl) return;
  int src = eli[wave];
  int dst = eli[nl + wave];
  int node = (lane < 32) ? src : dst;
  int sub = lane & 31;
  float2 v = __half22float2(((const __half2*)(z + (size_t)node * 64))[sub]);
  float ox = __shfl_xor(v.x, 32, 64);
  float oy = __shfl_xor(v.y, 32, 64);
  float p = v.x * ox + v.y * oy;
#pragma unroll
  for (int m = 16; m >= 1; m >>= 1) p += __shfl_xor(p, m, 64);
  if (lane == 0) out[wave] = p;
}

extern "C" void kernel_launch(void* const* d_in, const int* in_sizes, int n_in,
                              void* d_out, int out_size, void* d_ws, size_t ws_size,
                              hipStream_t stream) {
  const float* x  = (const float*)d_in[0];
  const float* W1 = (const float*)d_in[1];
  const float* b1 = (const float*)d_in[2];
  const float* W2 = (const float*)d_in[3];
  const float* b2 = (const float*)d_in[4];
  const int* eidx = (const int*)d_in[5];
  const int* eli  = (const int*)d_in[6];
  const int N  = in_sizes[0] / 128;
  const int E  = in_sizes[5] / 2;
  const int NL = in_sizes[6] / 2;
  float* out = (float*)d_out;

  char* ws = (char*)d_ws;
  size_t off = 0;
  auto alloc = [&](size_t bytes) -> char* {
    char* p = ws + off;
    off = (off + bytes + 255) & ~(size_t)255;
    return p;
  };
  const int B = (N + 255) / 256;        // buckets (col>>8); needs N <= 65536
  const int chunk = (E + NBLK - 1) / NBLK;
  float*    dis   = (float*)   alloc((size_t)N * 4);
  float*    dinv  = (float*)   alloc((size_t)N * 4);
  int*      cnt   = (int*)     alloc((size_t)N * 4);
  int*      rowp  = (int*)     alloc((size_t)(N + 1) * 4);
  int*      bhist = (int*)     alloc((size_t)NBLK * B * 4);
  int*      base  = (int*)     alloc((size_t)NBLK * B * 4);
  int*      bs    = (int*)     alloc((size_t)(B + 1) * 4);
  int2*     tmp   = (int2*)    alloc((size_t)E * 8);
  int*      ep    = (int*)     alloc((size_t)E * 4);
  _Float16* Xh    = (_Float16*)alloc((size_t)N * 128 * 2);
  _Float16* W1t   = (_Float16*)alloc((size_t)128 * 128 * 2);
  _Float16* W2t   = (_Float16*)alloc((size_t)64 * 128 * 2);
  __half*   bufA  = (__half*)  alloc((size_t)N * 128 * 2);
  __half*   bufB  = (__half*)  alloc((size_t)N * 128 * 2);
  __half*   bufC  = (__half*)  alloc((size_t)N * 64 * 2);
  __half*   z     = (__half*)  alloc((size_t)N * 64 * 2);
  (void)ws_size; (void)n_in; (void)out_size;

  const int* row = eidx;      // edge_index[0]
  const int* col = eidx + E;  // edge_index[1]

  const int n4 = N * 32;  // N*128/4 float4 groups
  prep_kernel<<<(n4 + 255) / 256, 256, 0, stream>>>(x, W1, W2, Xh, W1t, W2t, n4);
  // sort-based CSR build (no global atomics, slim edge pipeline)
  hist_kernel<<<NBLK, 256, 0, stream>>>(col, bhist, E, chunk, B);
  base_kernel<<<1, 256, 0, stream>>>(bhist, base, bs, B);
  bucket_scatter_kernel<<<NBLK, 256, 0, stream>>>(row, col, base, tmp, E, chunk, B);
  bucket_csr_kernel<<<B, 256, 0, stream>>>(tmp, bs, cnt, rowp, dis, dinv, ep, N);
  // conv1: bufA = half(Xh@W1); bufB = half(relu(agg(bufA)+dinv*bufA+b1))
  gemm_mfma_kernel<128><<<(N + 63) / 64, 256, 0, stream>>>(Xh, W1t, (_Float16*)bufA, N);
  agg128h_kernel<true><<<(N + 3) / 4, 256, 0, stream>>>(bufA, rowp, ep, dis, dinv, b1, bufB, N);
  // conv2: bufC = half(bufB@W2); z = half(agg(bufC)+dinv*bufC+b2)
  gemm_mfma_kernel<64><<<(N + 63) / 64, 256, 0, stream>>>((const _Float16*)bufB, W2t,
                                                          (_Float16*)bufC, N);
  agg64h_kernel<false><<<(N + 3) / 4, 256, 0, stream>>>(bufC, rowp, ep, dis, dinv, b2, z, N);
  // decode
  decode_kernel<<<(NL + 3) / 4, 256, 0, stream>>>(z, eli, out, NL);
}

// Round 14
// 258.640 us; speedup vs baseline: 1.0519x; 1.0099x over previous
//
#include <hip/hip_runtime.h>
#include <hip/hip_bf16.h>
#include <hip/hip_fp16.h>

// ---------------------------------------------------------------------------
// GCN link prediction (math fp32, fp16 tables, MFMA GEMMs):
//   prep | sort-based CSR build (no global atomics, ep = src only) ->
//   mfma gemm1 -> agg128 relu -> mfma gemm2 -> agg64 -> decode
// Round 14 = round-13 passing pipeline with ONE concept: quarter-wave edge
// parallelism in agg128/agg64 (4 edges per VMEM instruction; uniform-index
// shfl broadcasts + quarter select — the round-10-validated scheme, widened).
// ---------------------------------------------------------------------------

typedef _Float16 half8 __attribute__((ext_vector_type(8)));
typedef _Float16 half4v __attribute__((ext_vector_type(4)));
typedef float   floatx4 __attribute__((ext_vector_type(4)));

#define NBLK 256  // blocks for edge-chunk passes

// Convert x -> fp16 Xh; W1/W2 -> fp16 transposed (round-9 verbatim).
__global__ __launch_bounds__(256)
void prep_kernel(const float* __restrict__ x, const float* __restrict__ W1,
                 const float* __restrict__ W2, _Float16* __restrict__ Xh,
                 _Float16* __restrict__ W1t, _Float16* __restrict__ W2t, int n4) {
  int i = blockIdx.x * 256 + threadIdx.x;
  if (i < n4) {
    float4 v = ((const float4*)x)[i];
    half4v h; h[0] = (_Float16)v.x; h[1] = (_Float16)v.y;
    h[2] = (_Float16)v.z; h[3] = (_Float16)v.w;
    ((half4v*)Xh)[i] = h;
  }
  if (i < 128 * 128) {  // W1t[n*128+k] = W1[k*128+n]
    int k = i >> 7, n = i & 127;
    W1t[(size_t)n * 128 + k] = (_Float16)W1[i];
  }
  if (i < 128 * 64) {   // W2t[n*128+k] = W2[k*64+n]
    int k = i >> 6, n = i & 63;
    W2t[(size_t)n * 128 + k] = (_Float16)W2[i];
  }
}

// Pass A1: per-block LDS histogram of bucket = col>>8.
__global__ __launch_bounds__(256)
void hist_kernel(const int* __restrict__ col, int* __restrict__ bhist,
                 int ne, int chunk, int B) {
  __shared__ int h[256];
  int t = threadIdx.x, blk = blockIdx.x;
  for (int b = t; b < B; b += 256) h[b] = 0;
  __syncthreads();
  int e0 = blk * chunk, e1 = min(ne, e0 + chunk);
  for (int i = e0 + t; i < e1; i += 256)
    atomicAdd(&h[col[i] >> 8], 1);
  __syncthreads();
  for (int b = t; b < B; b += 256) bhist[blk * B + b] = h[b];
}

// Pass A2 (1 block): bucket totals, bucket starts bs[0..B], per-block bases.
__global__ __launch_bounds__(256)
void base_kernel(const int* __restrict__ bhist, int* __restrict__ base,
                 int* __restrict__ bs, int B) {
  __shared__ int tot[256];
  __shared__ int start[257];
  int t = threadIdx.x;
  if (t < B) {
    int s = 0;
    for (int blk = 0; blk < NBLK; ++blk) s += bhist[blk * B + t];
    tot[t] = s;
  }
  __syncthreads();
  if (t == 0) {
    int run = 0;
    for (int b = 0; b < B; ++b) { start[b] = run; run += tot[b]; }
    start[B] = run;
  }
  __syncthreads();
  if (t <= B) bs[t] = start[t];
  if (t < B) {
    int run = start[t];
    for (int blk = 0; blk < NBLK; ++blk) {
      base[blk * B + t] = run;
      run += bhist[blk * B + t];
    }
  }
}

// Pass A3: scatter edges into bucket-grouped tmp[(r,c)] via LDS cursors.
__global__ __launch_bounds__(256)
void bucket_scatter_kernel(const int* __restrict__ row, const int* __restrict__ col,
                           const int* __restrict__ base, int2* __restrict__ tmp,
                           int ne, int chunk, int B) {
  __shared__ int cur[256];
  int t = threadIdx.x, blk = blockIdx.x;
  for (int b = t; b < B; b += 256) cur[b] = base[blk * B + b];
  __syncthreads();
  int e0 = blk * chunk, e1 = min(ne, e0 + chunk);
  for (int i = e0 + t; i < e1; i += 256) {
    int c = col[i];
    int pos = atomicAdd(&cur[c >> 8], 1);
    tmp[pos] = make_int2(row[i], c);
  }
}

// Pass B1 (one block per bucket): 256-bin LDS histogram over col&255 ->
// rowp, dis, dinv, and final CSR scatter ep[pos] = src (LDS cursors).
__global__ __launch_bounds__(256)
void bucket_csr_kernel(const int2* __restrict__ tmp, const int* __restrict__ bs,
                       int* __restrict__ rowp, float* __restrict__ dis,
                       float* __restrict__ dinv, int* __restrict__ ep, int n) {
  __shared__ int h[256], lo[256], cur[256];
  int t = threadIdx.x, b = blockIdx.x;
  h[t] = 0;
  __syncthreads();
  int s0 = bs[b], s1 = bs[b + 1];
  for (int i = s0 + t; i < s1; i += 256)
    atomicAdd(&h[tmp[i].y & 255], 1);
  __syncthreads();
  if (t == 0) {
    int run = 0;
    for (int cb = 0; cb < 256; ++cb) { lo[cb] = run; run += h[cb]; }
  }
  __syncthreads();
  cur[t] = lo[t];
  int node = (b << 8) + t;
  if (node < n) {
    int c = h[t];
    rowp[node] = s0 + lo[t];
    float d = (float)(c + 1);   // +1 self loop
    dinv[node] = 1.0f / d;
    dis[node]  = rsqrtf(d);
    if (node == n - 1) rowp[n] = s1;   // last bucket end == E
  }
  __syncthreads();
  for (int i = s0 + t; i < s1; i += 256) {
    int2 rc = tmp[i];
    int r = atomicAdd(&cur[rc.y & 255], 1);
    ep[s0 + r] = rc.x;
  }
}

// Y[N,M] = Xh[N,128] @ Wt^T (Wt is [M][128], fp16). MFMA 16x16x32.
template<int M>
__global__ __launch_bounds__(256)
void gemm_mfma_kernel(const _Float16* __restrict__ Xh,
                      const _Float16* __restrict__ Wt,
                      _Float16* __restrict__ Y, int N) {
  constexpr int K = 128;
  constexpr int CT = M / 16;
  const int t = threadIdx.x;
  const int lane = t & 63;
  const int i16 = lane & 15;
  const int quad = lane >> 4;
  const int row0 = blockIdx.x * 64 + (t >> 6) * 16;
  int arow = row0 + i16;
  if (arow >= N) arow = N - 1;
  const _Float16* aptr = Xh + (size_t)arow * K + quad * 8;
  floatx4 acc[CT];
#pragma unroll
  for (int c = 0; c < CT; ++c) acc[c] = (floatx4){0.f, 0.f, 0.f, 0.f};
#pragma unroll
  for (int k0 = 0; k0 < K; k0 += 32) {
    half8 a = *(const half8*)(aptr + k0);
#pragma unroll
    for (int c = 0; c < CT; ++c) {
      half8 b = *(const half8*)(Wt + (size_t)(c * 16 + i16) * K + quad * 8 + k0);
      acc[c] = __builtin_amdgcn_mfma_f32_16x16x32_f16(a, b, acc[c], 0, 0, 0);
    }
  }
#pragma unroll
  for (int c = 0; c < CT; ++c) {
#pragma unroll
    for (int r = 0; r < 4; ++r) {
      int gr = row0 + quad * 4 + r;
      if (gr < N) Y[(size_t)gr * M + c * 16 + i16] = (_Float16)acc[c][r];
    }
  }
}

// Broadcast edge j's (src, dis) with UNIFORM shfl indices; zero weight if
// j >= m (src clamped to edge k's — always valid).
#define BCAST(j, svar, dvar)                          \
  {                                                   \
    int jj = (j) < m ? (j) : k;                       \
    svar = __shfl(er, jj, 64);                        \
    dvar = ((j) < m) ? __shfl(dr, jj, 64) : 0.f;      \
  }

// CH=128 aggregation: quarter-wave edge parallelism. 4 edges broadcast per
// group; quarter q takes edge k+q; lane loads 16B = 8 fp16 ch at sub*8
// (16 lanes x 16B = one full 256B row per quarter -> 4 rows per VMEM instr).
// 2 groups in flight (8 edges). Reduce via shfl_xor 16,32.
template<bool RELU>
__global__ __launch_bounds__(256)
void agg128h_kernel(const __half* __restrict__ xw, const int* __restrict__ row_ptr,
                    const int* __restrict__ ep, const float* __restrict__ dis,
                    const float* __restrict__ deg_inv, const float* __restrict__ bias,
                    __half* __restrict__ out, int n) {
  int wave = (blockIdx.x * 256 + threadIdx.x) >> 6;
  int lane = threadIdx.x & 63;
  if (wave >= n) return;
  const int node = wave;
  const int s0 = row_ptr[node], s1 = row_ptr[node + 1];
  const int sub = lane & 15;
  const int quarter = lane >> 4;
  const float disc = dis[node];
  float a0[8], a1[8];
#pragma unroll
  for (int j = 0; j < 8; ++j) { a0[j] = 0.f; a1[j] = 0.f; }
  for (int base = s0; base < s1; base += 64) {
    int m = s1 - base; if (m > 64) m = 64;   // wave-uniform
    int er = 0; float dr = 0.f;
    if (lane < m) { er = ep[base + lane]; dr = dis[er]; }
    for (int k = 0; k < m; k += 8) {
      // group A: edges k..k+3 (quarter q -> edge k+q)
      {
        int sA, sB, sC, sD; float dA, dB, dC, dD;
        BCAST(k,     sA, dA); BCAST(k + 1, sB, dB);
        BCAST(k + 2, sC, dC); BCAST(k + 3, sD, dD);
        int   s = (quarter == 0) ? sA : (quarter == 1) ? sB : (quarter == 2) ? sC : sD;
        float w = ((quarter == 0) ? dA : (quarter == 1) ? dB : (quarter == 2) ? dC : dD) * disc;
        float4 raw = ((const float4*)(xw + (size_t)s * 128))[sub];
        const __half2* hp = (const __half2*)&raw;
#pragma unroll
        for (int j = 0; j < 4; ++j) {
          float2 v = __half22float2(hp[j]);
          a0[2 * j]     = fmaf(w, v.x, a0[2 * j]);
          a0[2 * j + 1] = fmaf(w, v.y, a0[2 * j + 1]);
        }
      }
      // group B: edges k+4..k+7
      if (k + 4 < m) {
        int sA, sB, sC, sD; float dA, dB, dC, dD;
        BCAST(k + 4, sA, dA); BCAST(k + 5, sB, dB);
        BCAST(k + 6, sC, dC); BCAST(k + 7, sD, dD);
        int   s = (quarter == 0) ? sA : (quarter == 1) ? sB : (quarter == 2) ? sC : sD;
        float w = ((quarter == 0) ? dA : (quarter == 1) ? dB : (quarter == 2) ? dC : dD) * disc;
        float4 raw = ((const float4*)(xw + (size_t)s * 128))[sub];
        const __half2* hp = (const __half2*)&raw;
#pragma unroll
        for (int j = 0; j < 4; ++j) {
          float2 v = __half22float2(hp[j]);
          a1[2 * j]     = fmaf(w, v.x, a1[2 * j]);
          a1[2 * j + 1] = fmaf(w, v.y, a1[2 * j + 1]);
        }
      }
    }
  }
#pragma unroll
  for (int j = 0; j < 8; ++j) {
    a0[j] += a1[j];
    a0[j] += __shfl_xor(a0[j], 16, 64);
    a0[j] += __shfl_xor(a0[j], 32, 64);
  }
  if (quarter == 0) {
    float di = deg_inv[node];
    float4 sraw = ((const float4*)(xw + (size_t)node * 128))[sub];
    const __half2* sp = (const __half2*)&sraw;
    const float4* bp = (const float4*)(bias + 8 * sub);
    float o[8];
#pragma unroll
    for (int j = 0; j < 4; ++j) {
      float2 sv = __half22float2(sp[j]);
      o[2 * j]     = a0[2 * j]     + sv.x * di;
      o[2 * j + 1] = a0[2 * j + 1] + sv.y * di;
    }
    float4 b0 = bp[0], b1v = bp[1];
    o[0] += b0.x; o[1] += b0.y; o[2] += b0.z; o[3] += b0.w;
    o[4] += b1v.x; o[5] += b1v.y; o[6] += b1v.z; o[7] += b1v.w;
    if (RELU) {
#pragma unroll
      for (int j = 0; j < 8; ++j) o[j] = fmaxf(o[j], 0.f);
    }
    __half2 h2[4];
#pragma unroll
    for (int j = 0; j < 4; ++j)
      h2[j] = __float22half2_rn(make_float2(o[2 * j], o[2 * j + 1]));
    *(float4*)(out + (size_t)node * 128 + 8 * sub) = *(const float4*)h2;
  }
}

// CH=64 aggregation: quarter-wave; lane loads 8B = 4 fp16 ch at sub*4
// (16 lanes x 8B = full 128B row per quarter).
template<bool RELU>
__global__ __launch_bounds__(256)
void agg64h_kernel(const __half* __restrict__ xw, const int* __restrict__ row_ptr,
                   const int* __restrict__ ep, const float* __restrict__ dis,
                   const float* __restrict__ deg_inv, const float* __restrict__ bias,
                   __half* __restrict__ out, int n) {
  int wave = (blockIdx.x * 256 + threadIdx.x) >> 6;
  int lane = threadIdx.x & 63;
  if (wave >= n) return;
  const int node = wave;
  const int s0 = row_ptr[node], s1 = row_ptr[node + 1];
  const int sub = lane & 15;
  const int quarter = lane >> 4;
  const float disc = dis[node];
  float a0[4], a1[4];
#pragma unroll
  for (int j = 0; j < 4; ++j) { a0[j] = 0.f; a1[j] = 0.f; }
  for (int base = s0; base < s1; base += 64) {
    int m = s1 - base; if (m > 64) m = 64;
    int er = 0; float dr = 0.f;
    if (lane < m) { er = ep[base + lane]; dr = dis[er]; }
    for (int k = 0; k < m; k += 8) {
      {
        int sA, sB, sC, sD; float dA, dB, dC, dD;
        BCAST(k,     sA, dA); BCAST(k + 1, sB, dB);
        BCAST(k + 2, sC, dC); BCAST(k + 3, sD, dD);
        int   s = (quarter == 0) ? sA : (quarter == 1) ? sB : (quarter == 2) ? sC : sD;
        float w = ((quarter == 0) ? dA : (quarter == 1) ? dB : (quarter == 2) ? dC : dD) * disc;
        float2 raw = ((const float2*)(xw + (size_t)s * 64))[sub];
        const __half2* hp = (const __half2*)&raw;
#pragma unroll
        for (int j = 0; j < 2; ++j) {
          float2 v = __half22float2(hp[j]);
          a0[2 * j]     = fmaf(w, v.x, a0[2 * j]);
          a0[2 * j + 1] = fmaf(w, v.y, a0[2 * j + 1]);
        }
      }
      if (k + 4 < m) {
        int sA, sB, sC, sD; float dA, dB, dC, dD;
        BCAST(k + 4, sA, dA); BCAST(k + 5, sB, dB);
        BCAST(k + 6, sC, dC); BCAST(k + 7, sD, dD);
        int   s = (quarter == 0) ? sA : (quarter == 1) ? sB : (quarter == 2) ? sC : sD;
        float w = ((quarter == 0) ? dA : (quarter == 1) ? dB : (quarter == 2) ? dC : dD) * disc;
        float2 raw = ((const float2*)(xw + (size_t)s * 64))[sub];
        const __half2* hp = (const __half2*)&raw;
#pragma unroll
        for (int j = 0; j < 2; ++j) {
          float2 v = __half22float2(hp[j]);
          a1[2 * j]     = fmaf(w, v.x, a1[2 * j]);
          a1[2 * j + 1] = fmaf(w, v.y, a1[2 * j + 1]);
        }
      }
    }
  }
#pragma unroll
  for (int j = 0; j < 4; ++j) {
    a0[j] += a1[j];
    a0[j] += __shfl_xor(a0[j], 16, 64);
    a0[j] += __shfl_xor(a0[j], 32, 64);
  }
  if (quarter == 0) {
    float di = deg_inv[node];
    float2 sraw = ((const float2*)(xw + (size_t)node * 64))[sub];
    const __half2* sp = (const __half2*)&sraw;
    float4 bv = ((const float4*)(bias))[sub];
    float2 s0v = __half22float2(sp[0]);
    float2 s1v = __half22float2(sp[1]);
    float o0 = a0[0] + s0v.x * di + bv.x;
    float o1 = a0[1] + s0v.y * di + bv.y;
    float o2 = a0[2] + s1v.x * di + bv.z;
    float o3 = a0[3] + s1v.y * di + bv.w;
    if (RELU) {
      o0 = fmaxf(o0, 0.f); o1 = fmaxf(o1, 0.f);
      o2 = fmaxf(o2, 0.f); o3 = fmaxf(o3, 0.f);
    }
    __half2 h2[2];
    h2[0] = __float22half2_rn(make_float2(o0, o1));
    h2[1] = __float22half2_rn(make_float2(o2, o3));
    *(float2*)(out + (size_t)node * 64 + 4 * sub) = *(const float2*)h2;
  }
}

// Decode: half-wave src/dst split (round-10, passing).
__global__ __launch_bounds__(256)
void decode_kernel(const __half* __restrict__ z, const int* __restrict__ eli,
                   float* __restrict__ out, int nl) {
  int wave = (blockIdx.x * 256 + threadIdx.x) >> 6;
  int lane = threadIdx.x & 63;
  if (wave >= nl) return;
  int src = eli[wave];
  int dst = eli[nl + wave];
  int node = (lane < 32) ? src : dst;
  int sub = lane & 31;
  float2 v = __half22float2(((const __half2*)(z + (size_t)node * 64))[sub]);
  float ox = __shfl_xor(v.x, 32, 64);
  float oy = __shfl_xor(v.y, 32, 64);
  float p = v.x * ox + v.y * oy;
#pragma unroll
  for (int m = 16; m >= 1; m >>= 1) p += __shfl_xor(p, m, 64);
  if (lane == 0) out[wave] = p;
}

extern "C" void kernel_launch(void* const* d_in, const int* in_sizes, int n_in,
                              void* d_out, int out_size, void* d_ws, size_t ws_size,
                              hipStream_t stream) {
  const float* x  = (const float*)d_in[0];
  const float* W1 = (const float*)d_in[1];
  const float* b1 = (const float*)d_in[2];
  const float* W2 = (const float*)d_in[3];
  const float* b2 = (const float*)d_in[4];
  const int* eidx = (const int*)d_in[5];
  const int* eli  = (const int*)d_in[6];
  const int N  = in_sizes[0] / 128;
  const int E  = in_sizes[5] / 2;
  const int NL = in_sizes[6] / 2;
  float* out = (float*)d_out;

  char* ws = (char*)d_ws;
  size_t off = 0;
  auto alloc = [&](size_t bytes) -> char* {
    char* p = ws + off;
    off = (off + bytes + 255) & ~(size_t)255;
    return p;
  };
  const int B = (N + 255) / 256;        // buckets (col>>8); needs N <= 65536
  const int chunk = (E + NBLK - 1) / NBLK;
  float*    dis   = (float*)   alloc((size_t)N * 4);
  float*    dinv  = (float*)   alloc((size_t)N * 4);
  int*      rowp  = (int*)     alloc((size_t)(N + 1) * 4);
  int*      bhist = (int*)     alloc((size_t)NBLK * B * 4);
  int*      base  = (int*)     alloc((size_t)NBLK * B * 4);
  int*      bs    = (int*)     alloc((size_t)(B + 1) * 4);
  int2*     tmp   = (int2*)    alloc((size_t)E * 8);
  int*      ep    = (int*)     alloc((size_t)E * 4);
  _Float16* Xh    = (_Float16*)alloc((size_t)N * 128 * 2);
  _Float16* W1t   = (_Float16*)alloc((size_t)128 * 128 * 2);
  _Float16* W2t   = (_Float16*)alloc((size_t)64 * 128 * 2);
  __half*   bufA  = (__half*)  alloc((size_t)N * 128 * 2);
  __half*   bufB  = (__half*)  alloc((size_t)N * 128 * 2);
  __half*   bufC  = (__half*)  alloc((size_t)N * 64 * 2);
  __half*   z     = (__half*)  alloc((size_t)N * 64 * 2);
  (void)ws_size; (void)n_in; (void)out_size;

  const int* row = eidx;      // edge_index[0]
  const int* col = eidx + E;  // edge_index[1]

  const int n4 = N * 32;  // N*128/4 float4 groups
  prep_kernel<<<(n4 + 255) / 256, 256, 0, stream>>>(x, W1, W2, Xh, W1t, W2t, n4);
  // sort-based CSR build (no global atomics, slim edge pipeline)
  hist_kernel<<<NBLK, 256, 0, stream>>>(col, bhist, E, chunk, B);
  base_kernel<<<1, 256, 0, stream>>>(bhist, base, bs, B);
  bucket_scatter_kernel<<<NBLK, 256, 0, stream>>>(row, col, base, tmp, E, chunk, B);
  bucket_csr_kernel<<<B, 256, 0, stream>>>(tmp, bs, rowp, dis, dinv, ep, N);
  // conv1: bufA = half(Xh@W1); bufB = half(relu(agg(bufA)+dinv*bufA+b1))
  gemm_mfma_kernel<128><<<(N + 63) / 64, 256, 0, stream>>>(Xh, W1t, (_Float16*)bufA, N);
  agg128h_kernel<true><<<(N + 3) / 4, 256, 0, stream>>>(bufA, rowp, ep, dis, dinv, b1, bufB, N);
  // conv2: bufC = half(bufB@W2); z = half(agg(bufC)+dinv*bufC+b2)
  gemm_mfma_kernel<64><<<(N + 63) / 64, 256, 0, stream>>>((const _Float16*)bufB, W2t,
                                                          (_Float16*)bufC, N);
  agg64h_kernel<false><<<(N + 3) / 4, 256, 0, stream>>>(bufC, rowp, ep, dis, dinv, b2, z, N);
  // decode
  decode_kernel<<<(NL + 3) / 4, 256, 0, stream>>>(z, eli, out, NL);
}